// Round 9
// baseline (32.796 us; speedup 1.0000x reference)
//
#include <hip/hip_runtime.h>
#include <math.h>

#define MAGIC 0x5F3759DFu
typedef unsigned int u32;

__device__ __forceinline__ void bar_lds(){
  asm volatile("s_waitcnt lgkmcnt(0)\n\ts_barrier" ::: "memory");
}
__device__ __forceinline__ void bar_full(){
  asm volatile("s_waitcnt vmcnt(0) lgkmcnt(0)\n\ts_barrier" ::: "memory");
}
__device__ inline float wsum(float v){
  #pragma unroll
  for (int o=32;o;o>>=1) v += __shfl_xor(v,o,64);
  return v;
}
__device__ inline float wmax(float v){
  #pragma unroll
  for (int o=32;o;o>>=1) v = fmaxf(v,__shfl_xor(v,o,64));
  return v;
}
__device__ inline float hsum32(float v){
  #pragma unroll
  for (int o=16;o;o>>=1) v += __shfl_xor(v,o,64);
  return v;
}
__device__ __forceinline__ void stageW(const float* g, float* l, int nfloats,
                                       int wid, int lane){
  const int nch = nfloats>>8;
  for (int c=wid; c<nch; c+=8)
    __builtin_amdgcn_global_load_lds(
      (__attribute__((address_space(1))) u32*)(void*)(g+(c<<8)+(lane<<2)),
      (__attribute__((address_space(3))) u32*)(void*)(l+(c<<8)), 16, 0, 0);
}
__device__ __forceinline__ void pf(const float* p, int nfloats, int tid){
  float4 acc={0.f,0.f,0.f,0.f};
  const int nq=nfloats>>2;
  for (int i=tid;i<nq;i+=512){
    const float4 v=((const float4*)p)[i];
    acc.x+=v.x; acc.y+=v.y; acc.z+=v.z; acc.w+=v.w;
  }
  asm volatile("" :: "v"(acc.x),"v"(acc.y),"v"(acc.z),"v"(acc.w));
}

// ws float layout: p0@0 flag@256 | p1@320 flag@576 | h1@640 flag@896 | h2@960 flag@1216
__global__ __launch_bounds__(512,1) void net_kernel(
    const float* __restrict__ gp_x, const float* __restrict__ sp_x,
    const int* __restrict__ gp_src, const int* __restrict__ gp_dst,
    const int* __restrict__ sp_src, const int* __restrict__ sp_dst,
    const float* __restrict__ g_W0, const float* __restrict__ g_W,
    const float* __restrict__ g_b,  const float* __restrict__ g_pWrel,
    const float* __restrict__ g_pbrel, const float* __restrict__ g_pWroot,
    const float* __restrict__ g_linW, const float* __restrict__ g_linb,
    const float* __restrict__ s_W0, const float* __restrict__ s_W,
    const float* __restrict__ s_b,  const float* __restrict__ s_pWrel,
    const float* __restrict__ s_pbrel, const float* __restrict__ s_pWroot,
    const float* __restrict__ s_linW, const float* __restrict__ s_linb,
    const float* __restrict__ fcW, const float* __restrict__ fcb,
    const float* __restrict__ lnw, const float* __restrict__ lnb,
    float* __restrict__ wsbuf, float* __restrict__ out)
{
  __shared__ __align__(16) float slotA[16384];      // W1 -> W3 (DMA)
  __shared__ __align__(16) float XBx[16][128];
  __shared__ __align__(16) float ZB[8][128];
  __shared__ __align__(16) float PBf[5120];         // z0 / GEMM partials / tail aliases
  __shared__ __align__(16) float wrelL[512];
  __shared__ __align__(16) float wrootL[512];
  __shared__ __align__(16) float Adn[256];          // dense norm-adj (pool folded)
  __shared__ __align__(16) float Mdn[256];          // dense edge-count matrix
  __shared__ float d1P[32], d2P[32];
  __shared__ float wpart[16];
  __shared__ float tsA[8];
  __shared__ int   permA[8];

  const int lt  = threadIdx.x;
  const int bid = blockIdx.x;
  const int wid = lt>>6, lane = lt&63;
  float* const fcin = &PBf[4608];
  float* const yA   = &PBf[4864];

  // ============== prefetch army (bids 5,6,8,9; 7 idle) ==============
  if (bid >= 5){
    switch(bid){
      case 5: pf(g_linW,16384,lt); break;
      case 6: pf(s_linW,16384,lt); break;
      case 8: pf(g_W0,5760,lt); pf(g_W,32768,lt); pf(g_W+32768,16384,lt);
              pf(fcW,32768,lt); break;
      case 9: pf(s_W0,5760,lt); pf(s_W,32768,lt); pf(s_W+32768,16384,lt);
              pf(fcW+32768,32768,lt); break;
      default: break;
    }
    return;
  }

  // ============== FC pipeline blocks (bids 2,3,4 -> fc layers 1,2,3) ==============
  if (bid >= 2){
    const int L = bid-1;                       // 1,2,3
    const int qfc=(wid<<3)+(lane&7), f0fc=(lane>>3)<<5;
    float4 wr[32];
    #pragma unroll
    for (int t=0;t<32;++t) wr[t]=*(const float4*)(fcW+(L<<16)+(f0fc+t)*256+(qfc<<2));
    const float4 bb=*(const float4*)(fcb+(L<<8)+(qfc<<2));
    float4 lw={0,0,0,0}, lb2={0,0,0,0};
    if (L<3){ lw=*(const float4*)(lnw+(L<<8)+(qfc<<2)); lb2=*(const float4*)(lnb+(L<<8)+(qfc<<2)); }
    float b0=0.f,w0=0.f,l0=0.f;
    if (bid==2 && lt<256){ b0=fcb[lt]; w0=lnw[lt]; l0=lnb[lt]; }

    if (bid==2){
      if (lt==0){
        const u32* f1=(const u32*)(wsbuf+256);
        const u32* f2=(const u32*)(wsbuf+576);
        while (__hip_atomic_load(f1,__ATOMIC_ACQUIRE,__HIP_MEMORY_SCOPE_AGENT)!=MAGIC ||
               __hip_atomic_load(f2,__ATOMIC_ACQUIRE,__HIP_MEMORY_SCOPE_AGENT)!=MAGIC)
          __builtin_amdgcn_s_sleep(1);
      }
      bar_lds();
      float h=0.f;
      if (lt<256){
        h = __hip_atomic_load(wsbuf+lt,    __ATOMIC_RELAXED,__HIP_MEMORY_SCOPE_AGENT)
          + __hip_atomic_load(wsbuf+320+lt,__ATOMIC_RELAXED,__HIP_MEMORY_SCOPE_AGENT) + b0;
        float s=wsum(h), s2=wsum(h*h);
        if (lane==0){ wpart[wid]=s; wpart[8+wid]=s2; }
      }
      bar_lds();
      if (lt<256){
        const float S =wpart[0]+wpart[1]+wpart[2]+wpart[3];
        const float S2=wpart[8]+wpart[9]+wpart[10]+wpart[11];
        const float mu=S*(1.f/256.f);
        const float ri=rsqrtf(S2*(1.f/256.f)-mu*mu+1e-5f);
        fcin[lt]=fmaxf((h-mu)*ri*w0+l0,0.f);
      }
      bar_lds();
    } else {
      const int src=(bid==3)?640:960, fl=(bid==3)?896:1216;
      if (lt==0){
        const u32* f1=(const u32*)(wsbuf+fl);
        while (__hip_atomic_load(f1,__ATOMIC_ACQUIRE,__HIP_MEMORY_SCOPE_AGENT)!=MAGIC)
          __builtin_amdgcn_s_sleep(1);
      }
      bar_lds();
      if (lt<256) fcin[lt]=__hip_atomic_load(wsbuf+src+lt,__ATOMIC_RELAXED,__HIP_MEMORY_SCOPE_AGENT);
      bar_lds();
    }
    float4 a={0.f,0.f,0.f,0.f};
    #pragma unroll
    for (int t=0;t<32;++t){
      const float zv=fcin[f0fc+t];
      a.x+=zv*wr[t].x; a.y+=zv*wr[t].y; a.z+=zv*wr[t].z; a.w+=zv*wr[t].w;
    }
    #pragma unroll
    for (int m=8;m<64;m<<=1){
      a.x+=__shfl_xor(a.x,m,64); a.y+=__shfl_xor(a.y,m,64);
      a.z+=__shfl_xor(a.z,m,64); a.w+=__shfl_xor(a.w,m,64);
    }
    if (bid==4){
      if (lane<8){
        float4 r; r.x=a.x+bb.x; r.y=a.y+bb.y; r.z=a.z+bb.z; r.w=a.w+bb.w;
        *(float4*)(out+(qfc<<2))=r;
      }
      return;
    }
    const bool act=(lane<8);
    float4 hv={0.f,0.f,0.f,0.f};
    if (act){
      hv.x=a.x+bb.x; hv.y=a.y+bb.y; hv.z=a.z+bb.z; hv.w=a.w+bb.w;
      float s=hv.x+hv.y+hv.z+hv.w;
      float s2=hv.x*hv.x+hv.y*hv.y+hv.z*hv.z+hv.w*hv.w;
      #pragma unroll
      for (int m=1;m<8;m<<=1){ s+=__shfl_xor(s,m,64); s2+=__shfl_xor(s2,m,64); }
      if (lane==0){ wpart[wid]=s; wpart[8+wid]=s2; }
    }
    bar_lds();
    if (act){
      float S=0.f,S2=0.f;
      #pragma unroll
      for (int w2=0;w2<8;++w2){ S+=wpart[w2]; S2+=wpart[8+w2]; }
      const float mu=S*(1.f/256.f);
      const float ri=rsqrtf(S2*(1.f/256.f)-mu*mu+1e-5f);
      float* dst=wsbuf + ((bid==2)?640:960) + (qfc<<2);
      __hip_atomic_store(dst+0,fmaxf((hv.x-mu)*ri*lw.x+lb2.x,0.f),__ATOMIC_RELAXED,__HIP_MEMORY_SCOPE_AGENT);
      __hip_atomic_store(dst+1,fmaxf((hv.y-mu)*ri*lw.y+lb2.y,0.f),__ATOMIC_RELAXED,__HIP_MEMORY_SCOPE_AGENT);
      __hip_atomic_store(dst+2,fmaxf((hv.z-mu)*ri*lw.z+lb2.z,0.f),__ATOMIC_RELAXED,__HIP_MEMORY_SCOPE_AGENT);
      __hip_atomic_store(dst+3,fmaxf((hv.w-mu)*ri*lw.w+lb2.w,0.f),__ATOMIC_RELAXED,__HIP_MEMORY_SCOPE_AGENT);
    }
    __threadfence();
    bar_lds();
    if (lt==0) __hip_atomic_store((u32*)(wsbuf+((bid==2)?896:1216)),MAGIC,__ATOMIC_RELEASE,__HIP_MEMORY_SCOPE_AGENT);
    return;
  }

  // ============== GNN branch blocks (bids 0,1) ==============
  const int br = bid;
  const float* x0    = br ? sp_x    : gp_x;
  const int*   srcg  = br ? sp_src  : gp_src;
  const int*   dstg  = br ? sp_dst  : gp_dst;
  const float* W0    = br ? s_W0    : g_W0;
  const float* Wl    = br ? s_W     : g_W;
  const float* bl    = br ? s_b     : g_b;
  const float* wrel  = br ? s_pWrel : g_pWrel;
  const float* brel  = br ? s_pbrel : g_pbrel;
  const float* wroot = br ? s_pWroot: g_pWroot;
  const float* linWg = br ? s_linW  : g_linW;
  const float* linb  = br ? s_linb  : g_linb;
  float* wsOut = wsbuf + (br?320:0);
  u32*   wsFlag = (u32*)(wsbuf + (br?576:256));

  // ---- t0 register preloads (all OLDER than any DMA) ----
  float xv[4];
  #pragma unroll
  for (int r=0;r<4;++r){
    const int i=lt+(r<<9), v=i>>7, f=i&127;
    xv[r] = (f<45)? x0[v*45+f] : 0.f;
  }
  int es=0, ed=0; float emk=0.f;
  if (lt<64){ es=srcg[lt]; ed=dstg[lt]; emk=1.f; }
  const float4 brelv = *(const float4*)brel;
  float4 blv[4];
  #pragma unroll
  for (int L=0;L<4;++L) blv[L]=*(const float4*)(bl + L*128 + ((lt&31)<<2));
  const float linb_s = (lt<128)? linb[lt] : 0.f;
  asm volatile("" ::: "memory");
  // tiny DMA: score weights (1KB each)
  stageW(wrel,  wrelL,  512, wid, lane);
  stageW(wroot, wrootL, 512, wid, lane);

  // dense A/M builder (wave0 only; per-cell summands identical -> deterministic)
  auto build_dense = [&](int kk, float wlane, bool with_ts){
    const float4 z4={0.f,0.f,0.f,0.f};
    *(float4*)&Adn[lt<<2]=z4;
    *(float4*)&Mdn[lt<<2]=z4;
    const bool act=(emk!=0.f);
    int mycnt=0;
    for (int v=0;v<kk;++v){
      const unsigned long long m=__ballot(act && (ed==v));
      if (lt==v) mycnt=__popcll(m);
    }
    const float dinvlane=rsqrtf(1.f+(float)mycnt);
    const float dvs=__shfl(dinvlane,es,64);
    const float dvd=__shfl(dinvlane,ed,64);
    if (act){
      atomicAdd(&Adn[ed*16+es], dvs*dvd*wlane);
      atomicAdd(&Mdn[ed*16+es], 1.f);
    }
    if (lt<kk){
      const float tv = with_ts ? tsA[lt] : 1.f;
      atomicAdd(&Adn[lt*17], dinvlane*dinvlane*tv);
    }
  };
  auto do_E = [&](int n, int k, float bv, bool rebuild){
    if (lt<64){
      float sc=-INFINITY;
      if (lt<n){
        float acc=d2P[2*lt]+d2P[2*lt+1]+bv;
        for (int u=0;u<n;++u)
          acc += Mdn[lt*16+u]*(d1P[2*u]+d1P[2*u+1]);
        sc=acc;
      }
      int rank=0;
      for (int u=0;u<n;++u){
        const float su=__shfl(sc,u,64);
        rank += (su>sc || (su==sc && u<lt)) ? 1:0;
      }
      const int kept=(lt<n && rank<k)?1:0;
      const int pos=kept?rank:0;
      const float tval=kept?tanhf(sc):0.f;
      if (kept){ permA[rank]=lt; tsA[rank]=tval; }
      const float ts_src=__shfl(tval,es,64);
      const int ks=__shfl(kept,es,64), kd=__shfl(kept,ed,64);
      const int ps=__shfl(pos,es,64),  pd=__shfl(pos,ed,64);
      emk *= (float)(ks&kd);
      es=ps; ed=pd;
      if (rebuild) build_dense(k, ts_src, true);
    }
  };
  auto do_B = [&](int n){
    if (lt < (n<<5)){
      const int v=lt>>5, j4=(lt&31)<<2;
      float4 a={0.f,0.f,0.f,0.f};
      for (int u=0;u<n;++u){
        const float w=Adn[v*16+u];
        const float4 xs=*(const float4*)&XBx[permA[u]][j4];
        a.x+=w*xs.x; a.y+=w*xs.y; a.z+=w*xs.z; a.w+=w*xs.w;
      }
      *(float4*)&ZB[v][j4]=a;
    }
  };
  // C main: RB rows/task, S=4 f-split; Wb in LDS or global
  auto cmain = [&](const float* Wb, int nact, int R){
    if (lt<nact){
      const int c4=lt&31, s=(lt>>5)&3, f0=s<<5;
      const int r0=(nact==256)? ((lt>>7)<<2) : 0;
      float4 a0={0,0,0,0},a1=a0,a2=a0,a3=a0;
      for (int bb=0;bb<4;++bb){
        float4 wq[8];
        #pragma unroll
        for (int t=0;t<8;++t) wq[t]=*(const float4*)&Wb[(f0+(bb<<3)+t)*128+(c4<<2)];
        #pragma unroll
        for (int t=0;t<8;++t){
          const int f=f0+(bb<<3)+t;
          const float z0=ZB[r0+0][f], z1=ZB[r0+1][f];
          a0.x+=z0*wq[t].x; a0.y+=z0*wq[t].y; a0.z+=z0*wq[t].z; a0.w+=z0*wq[t].w;
          a1.x+=z1*wq[t].x; a1.y+=z1*wq[t].y; a1.z+=z1*wq[t].z; a1.w+=z1*wq[t].w;
          if (R==4){
            const float z2=ZB[r0+2][f], z3=ZB[r0+3][f];
            a2.x+=z2*wq[t].x; a2.y+=z2*wq[t].y; a2.z+=z2*wq[t].z; a2.w+=z2*wq[t].w;
            a3.x+=z3*wq[t].x; a3.y+=z3*wq[t].y; a3.z+=z3*wq[t].z; a3.w+=z3*wq[t].w;
          }
        }
      }
      float4* P4=(float4*)PBf;
      const int pb=lt*5;
      P4[pb]=a0; P4[pb+1]=a1;
      if (R==4){ P4[pb+2]=a2; P4[pb+3]=a3; }
    }
  };
  auto creduce = [&](int layer, int n, float4 bl4){
    if (lt < (n<<5)){
      const int v=lt>>5, c4=lt&31;
      const int base=(n==8)? ((v>>2)<<7) : 0;
      const int row =(n==8)? (v&3) : v;
      float4 acc=bl4;
      #pragma unroll
      for (int s=0;s<4;++s){
        const float4 p=((const float4*)PBf)[(base+(s<<5)+c4)*5+row];
        acc.x+=p.x; acc.y+=p.y; acc.z+=p.z; acc.w+=p.w;
      }
      float4 o;
      o.x=fmaxf(acc.x,0.f); o.y=fmaxf(acc.y,0.f);
      o.z=fmaxf(acc.z,0.f); o.w=fmaxf(acc.w,0.f);
      *(float4*)&XBx[v][c4<<2]=o;
      const float4 wr4=*(const float4*)&wrelL[(layer<<7)+(c4<<2)];
      const float4 wo4=*(const float4*)&wrootL[(layer<<7)+(c4<<2)];
      float p1=o.x*wr4.x+o.y*wr4.y+o.z*wr4.z+o.w*wr4.w;
      float p2=o.x*wo4.x+o.y*wo4.y+o.z*wo4.z+o.w*wo4.w;
      p1=hsum32(p1); p2=hsum32(p2);
      if ((lane&31)==0){ d1P[2*v]=p1; d1P[2*v+1]=0.f; d2P[2*v]=p2; d2P[2*v+1]=0.f; }
    }
  };

  // ---- phase 1: stage x + build layer-0 A/M ----
  #pragma unroll
  for (int r=0;r<4;++r){
    const int i=lt+(r<<9), v=i>>7, f=i&127;
    XBx[v][f]=xv[r];
  }
  if (lt<64) build_dense(16, 1.f, false);
  bar_lds();

  // ---- B0: z0 = A@x -> PBf[16][48] ----
  if (lt<256){
    const int v=lt>>4, j4=(lt&15)<<2;
    if (j4<48){
      float4 a={0.f,0.f,0.f,0.f};
      for (int u=0;u<16;++u){
        const float w=Adn[v*16+u];
        const float4 xs=*(const float4*)&XBx[u][j4];
        a.x+=w*xs.x; a.y+=w*xs.y; a.z+=w*xs.z; a.w+=w*xs.w;
      }
      *(float4*)&PBf[v*48+j4]=a;
    }
  }
  bar_full();   // drain wrel/wroot DMA (tiny)

  // ---- C0: x = relu(z0 @ W0 + b0)  (W0 global; NO DMA outstanding) ----
  {
    const int v=lt>>5, j4=(lt&31)<<2;
    const float* zrow=&PBf[v*48];
    float4 a={0.f,0.f,0.f,0.f};
    #pragma unroll
    for (int bb=0;bb<2;++bb){
      float4 wr[16]; float zr[16];
      #pragma unroll
      for (int t=0;t<16;++t){ wr[t]=*(const float4*)(W0+(bb*16+t)*128+j4); zr[t]=zrow[bb*16+t]; }
      #pragma unroll
      for (int t=0;t<16;++t){ a.x+=zr[t]*wr[t].x; a.y+=zr[t]*wr[t].y; a.z+=zr[t]*wr[t].z; a.w+=zr[t]*wr[t].w; }
    }
    { float4 wr[13]; float zr[13];
      #pragma unroll
      for (int t=0;t<13;++t){ wr[t]=*(const float4*)(W0+(32+t)*128+j4); zr[t]=zrow[32+t]; }
      #pragma unroll
      for (int t=0;t<13;++t){ a.x+=zr[t]*wr[t].x; a.y+=zr[t]*wr[t].y; a.z+=zr[t]*wr[t].z; a.w+=zr[t]*wr[t].w; }
    }
    float4 o;
    o.x=fmaxf(a.x+blv[0].x,0.f); o.y=fmaxf(a.y+blv[0].y,0.f);
    o.z=fmaxf(a.z+blv[0].z,0.f); o.w=fmaxf(a.w+blv[0].w,0.f);
    *(float4*)&XBx[v][j4]=o;
    const float4 wr4=*(const float4*)&wrelL[j4];
    const float4 wo4=*(const float4*)&wrootL[j4];
    float p1=o.x*wr4.x+o.y*wr4.y+o.z*wr4.z+o.w*wr4.w;
    float p2=o.x*wo4.x+o.y*wo4.y+o.z*wo4.z+o.w*wo4.w;
    p1=hsum32(p1); p2=hsum32(p2);
    if ((lane&31)==0){ d1P[2*v]=p1; d1P[2*v+1]=0.f; d2P[2*v]=p2; d2P[2*v+1]=0.f; }
  }
  stageW(Wl, slotA, 16384, wid, lane);        // W1 -> slotA (issued post-C0 loads)
  bar_lds();

  do_E(16, 8, brelv.x, true);  bar_lds();     // E0
  do_B(8);                     bar_full();    // B1; drain W1
  cmain(slotA, 256, 4);        bar_lds();     // C1m (LDS)
  creduce(1, 8, blv[1]);       bar_lds();     // C1r
  do_E(8, 4, brelv.y, true);   bar_lds();     // E1
  do_B(4);                     bar_lds();     // B2
  cmain(Wl+16384, 128, 4);     bar_lds();     // C2m (W2 global, L2-warm; no DMA out)
  stageW(Wl+32768, slotA, 16384, wid, lane);  // W3 -> slotA (slotA dead since C1m)
  creduce(2, 4, blv[2]);       bar_lds();     // C2r
  do_E(4, 2, brelv.z, true);   bar_lds();     // E2
  do_B(2);                     bar_full();    // B3; drain W3
  cmain(slotA, 128, 2);        bar_lds();     // C3m (LDS)
  creduce(3, 2, blv[3]);       bar_lds();     // C3r
  do_E(2, 1, brelv.w, false);  bar_lds();     // E3 (final perm/ts only)

  // ---- fcW-L0 half preload (flies under readout/softmax; no DMA outstanding) ----
  const int qg=lt&63, fhg=lt>>6;
  float4 wfc[16];
  #pragma unroll
  for (int t=0;t<16;++t)
    wfc[t]=*(const float4*)(fcW + (br*128 + fhg*16 + t)*256 + (qg<<2));

  // ---- readout main: partial dots of x[perm0] @ linW (global, coalesced) ----
  {
    const int oj=lt&127, fh=lt>>7;
    const int prow=permA[0];
    float p=0.f;
    #pragma unroll
    for (int i=0;i<32;++i){
      const int f=(fh<<5)+i;
      p += XBx[prow][f]*linWg[f*128+oj];
    }
    PBf[(fh<<7)+oj]=p;
  }
  bar_lds();
  if (lt<128){
    const float y=PBf[lt]+PBf[128+lt]+PBf[256+lt]+PBf[384+lt];
    yA[lt]=y*tsA[0]+linb_s;
  }
  bar_lds();
  // ---- log-softmax ----
  if (lt<128){
    const int ln=lt&63;
    const float a0=yA[ln], b0=yA[64+ln];
    const float m=wmax(fmaxf(a0,b0));
    const float sum=wsum(expf(a0-m)+expf(b0-m));
    const float lse=m+logf(sum);
    fcin[lt]=yA[lt]-lse;
  }
  bar_lds();
  // ---- fused FC-L0 half GEMV: partial = logprobs @ fcW[br*128:...] ----
  {
    float4 acc={0.f,0.f,0.f,0.f};
    #pragma unroll
    for (int t=0;t<16;++t){
      const float zv=fcin[fhg*16+t];
      acc.x+=zv*wfc[t].x; acc.y+=zv*wfc[t].y; acc.z+=zv*wfc[t].z; acc.w+=zv*wfc[t].w;
    }
    ((float4*)PBf)[(fhg<<6)+qg]=acc;
  }
  bar_lds();
  if (lt<64){
    float4 a={0.f,0.f,0.f,0.f};
    #pragma unroll
    for (int fh=0;fh<8;++fh){
      const float4 p=((const float4*)PBf)[(fh<<6)+lt];
      a.x+=p.x; a.y+=p.y; a.z+=p.z; a.w+=p.w;
    }
    float* dst=wsOut+(lt<<2);
    __hip_atomic_store(dst+0,a.x,__ATOMIC_RELAXED,__HIP_MEMORY_SCOPE_AGENT);
    __hip_atomic_store(dst+1,a.y,__ATOMIC_RELAXED,__HIP_MEMORY_SCOPE_AGENT);
    __hip_atomic_store(dst+2,a.z,__ATOMIC_RELAXED,__HIP_MEMORY_SCOPE_AGENT);
    __hip_atomic_store(dst+3,a.w,__ATOMIC_RELAXED,__HIP_MEMORY_SCOPE_AGENT);
  }
  __threadfence();
  bar_lds();
  if (lt==0) __hip_atomic_store(wsFlag,MAGIC,__ATOMIC_RELEASE,__HIP_MEMORY_SCOPE_AGENT);
}

extern "C" void kernel_launch(void* const* d_in, const int* in_sizes, int n_in,
                              void* d_out, int out_size, void* d_ws, size_t ws_size,
                              hipStream_t stream){
  // setup_inputs() DICT order (fc/ln block precedes gnn params):
  //  0 gp_x  1 sp_x  2 gp_src  3 gp_dst  4 sp_src  5 sp_dst
  //  6 fcW   7 fcb   8 lnw     9 lnb
  // 10 g_W0 11 g_W  12 g_b   13 g_pWrel 14 g_pbrel 15 g_pWroot 16 g_linW 17 g_linb
  // 18 s_W0 19 s_W  20 s_b   21 s_pWrel 22 s_pbrel 23 s_pWroot 24 s_linW 25 s_linb
  net_kernel<<<10,512,0,stream>>>(
    (const float*)d_in[0],(const float*)d_in[1],
    (const int*)d_in[2],(const int*)d_in[3],(const int*)d_in[4],(const int*)d_in[5],
    (const float*)d_in[10],(const float*)d_in[11],(const float*)d_in[12],(const float*)d_in[13],
    (const float*)d_in[14],(const float*)d_in[15],(const float*)d_in[16],(const float*)d_in[17],
    (const float*)d_in[18],(const float*)d_in[19],(const float*)d_in[20],(const float*)d_in[21],
    (const float*)d_in[22],(const float*)d_in[23],(const float*)d_in[24],(const float*)d_in[25],
    (const float*)d_in[6],(const float*)d_in[7],(const float*)d_in[8],(const float*)d_in[9],
    (float*)d_ws,(float*)d_out);
}

// Round 10
// 27.406 us; speedup vs baseline: 1.1967x; 1.1967x over previous
//
#include <hip/hip_runtime.h>
#include <math.h>

#define MAGIC 0x5F3759DFu
typedef unsigned int u32;

__device__ __forceinline__ void bar_lds(){
  asm volatile("s_waitcnt lgkmcnt(0)\n\ts_barrier" ::: "memory");
}
__device__ __forceinline__ void bar_vm0(){
  asm volatile("s_waitcnt vmcnt(0) lgkmcnt(0)\n\ts_barrier" ::: "memory");
}
// counted: allow 8 youngest VMEM ops (one in-flight stageW) to keep flying
__device__ __forceinline__ void bar_vm8(){
  asm volatile("s_waitcnt vmcnt(8) lgkmcnt(0)\n\ts_barrier" ::: "memory");
}

__device__ inline float wsum(float v){
  #pragma unroll
  for (int o=32;o;o>>=1) v += __shfl_xor(v,o,64);
  return v;
}
__device__ inline float wmax(float v){
  #pragma unroll
  for (int o=32;o;o>>=1) v = fmaxf(v,__shfl_xor(v,o,64));
  return v;
}
__device__ inline float hsum32(float v){
  #pragma unroll
  for (int o=16;o;o>>=1) v += __shfl_xor(v,o,64);
  return v;
}
__device__ __forceinline__ void stageW(const float* g, float* l, int nfloats,
                                       int wid, int lane){
  const int nch = nfloats>>8;
  for (int c=wid; c<nch; c+=8)
    __builtin_amdgcn_global_load_lds(
      (__attribute__((address_space(1))) u32*)(void*)(g+(c<<8)+(lane<<2)),
      (__attribute__((address_space(3))) u32*)(void*)(l+(c<<8)), 16, 0, 0);
}
__device__ __forceinline__ void pf(const float* p, int nfloats, int tid){
  float4 acc={0.f,0.f,0.f,0.f};
  const int nq=nfloats>>2;
  for (int i=tid;i<nq;i+=512){
    const float4 v=((const float4*)p)[i];
    acc.x+=v.x; acc.y+=v.y; acc.z+=v.z; acc.w+=v.w;
  }
  asm volatile("" :: "v"(acc.x),"v"(acc.y),"v"(acc.z),"v"(acc.w));
}

// fused C-phase for GNN layers 1..3: GEMV f-split with in-wave shfl reduce,
// relu+bias+score-dot epilogue; per-wave hsum -> d1P/d2P[(v<<2)+part]
template<int L>
__device__ __forceinline__ void cfused(int lt, const float* slot, const float* ZBp,
    float (*XB)[128], const float* wrelL, const float* wrootL,
    float4 blv, float* d1P, float* d2P){
  const int SPL=1<<L, CH=128>>L;
  const int o=lt>>L, part=lt&(SPL-1);
  const int v=o>>5, c4=o&31, f0=part*CH;
  const float* zrow = ZBp + v*128;
  float4 a={0.f,0.f,0.f,0.f};
  #pragma unroll
  for (int f=0; f<CH; ++f){
    const float zv=zrow[f0+f];
    const float4 w4=*(const float4*)&slot[(f0+f)*128+(c4<<2)];
    a.x+=zv*w4.x; a.y+=zv*w4.y; a.z+=zv*w4.z; a.w+=zv*w4.w;
  }
  #pragma unroll
  for (int m=1;m<SPL;m<<=1){
    a.x+=__shfl_xor(a.x,m,64); a.y+=__shfl_xor(a.y,m,64);
    a.z+=__shfl_xor(a.z,m,64); a.w+=__shfl_xor(a.w,m,64);
  }
  float p1=0.f,p2=0.f;
  if (part==0){
    float4 ox;
    ox.x=fmaxf(a.x+blv.x,0.f); ox.y=fmaxf(a.y+blv.y,0.f);
    ox.z=fmaxf(a.z+blv.z,0.f); ox.w=fmaxf(a.w+blv.w,0.f);
    *(float4*)&XB[v][c4<<2]=ox;
    const float4 wr4=*(const float4*)&wrelL[(L<<7)+(c4<<2)];
    const float4 wo4=*(const float4*)&wrootL[(L<<7)+(c4<<2)];
    p1=ox.x*wr4.x+ox.y*wr4.y+ox.z*wr4.z+ox.w*wr4.w;
    p2=ox.x*wo4.x+ox.y*wo4.y+ox.z*wo4.z+ox.w*wo4.w;
  }
  p1=wsum(p1); p2=wsum(p2);
  const int wid=lt>>6, lane=lt&63;
  if (lane==0){
    const int vv=wid>>(L-1), wp=wid&((1<<(L-1))-1);
    d1P[(vv<<2)+wp]=p1; d2P[(vv<<2)+wp]=p2;
  }
}

// ws float layout: p_g[0..127] flag@128 | p_s[256..383] flag@384
// H0[512..767] flag@768 | H1[1024..1279] flag@1280 | H2[1536..1791] flag@1792
__global__ __launch_bounds__(512,1) void net_kernel(
    const float* __restrict__ gp_x, const float* __restrict__ sp_x,
    const int* __restrict__ gp_src, const int* __restrict__ gp_dst,
    const int* __restrict__ sp_src, const int* __restrict__ sp_dst,
    const float* __restrict__ g_W0, const float* __restrict__ g_W,
    const float* __restrict__ g_b,  const float* __restrict__ g_pWrel,
    const float* __restrict__ g_pbrel, const float* __restrict__ g_pWroot,
    const float* __restrict__ g_linW, const float* __restrict__ g_linb,
    const float* __restrict__ s_W0, const float* __restrict__ s_W,
    const float* __restrict__ s_b,  const float* __restrict__ s_pWrel,
    const float* __restrict__ s_pbrel, const float* __restrict__ s_pWroot,
    const float* __restrict__ s_linW, const float* __restrict__ s_linb,
    const float* __restrict__ fcW, const float* __restrict__ fcb,
    const float* __restrict__ lnw, const float* __restrict__ lnb,
    float* __restrict__ wsbuf, float* __restrict__ out)
{
  __shared__ __align__(16) float slotA[16384];   // W1 -> W3 (DMA)
  __shared__ __align__(16) float slotB[16384];   // W2 -> linW (DMA)
  __shared__ __align__(16) float XBx[16][128];
  __shared__ __align__(16) float ZBraw[1024];    // z0[16][48] then ZB[8][128]
  __shared__ __align__(16) float wrelL[512], wrootL[512];
  __shared__ __align__(16) float Adn[256], Mdn[256];
  __shared__ float d1P[64], d2P[64];
  __shared__ float yA[128];
  __shared__ float tsA[8]; __shared__ int permA[8];
  __shared__ float fcin[256]; __shared__ float wpart[16];

  const int lt  = threadIdx.x;
  const int bid = blockIdx.x;
  const int wid = lt>>6, lane = lt&63;

  // ============ prefetch army (bids 6..14) — verbatim R8 ============
  if (bid >= 6){
    switch(bid){
      case 8:  pf(g_W0,5760,lt);        pf(g_W,32768,lt);      break;
      case 9:  pf(s_W0,5760,lt);        pf(s_W,32768,lt);      break;
      case 6:  pf(g_W+32768,16384,lt);  pf(g_linW,16384,lt);
               pf(g_pWrel,512,lt);      pf(g_pWroot,512,lt);   break;
      case 7:  pf(s_W+32768,16384,lt);  pf(s_linW,16384,lt);
               pf(s_pWrel,512,lt);      pf(s_pWroot,512,lt);   break;
      case 10: pf(fcW,65536,lt);        break;
      case 11: pf(fcW+65536,65536,lt);  break;
      case 12: pf(fcW+131072,65536,lt); break;
      case 13: pf(fcW+196608,65536,lt); break;
      case 14: pf(fcb,1024,lt); pf(lnw,768,lt); pf(lnb,768,lt); break;
      default: break;
    }
    return;
  }

  // ============ FC pipeline blocks (bids 2..5, L=bid-2) — verbatim R8 ============
  if (bid >= 2){
    const int L = bid-2;
    const int qfc=(wid<<3)+(lane&7), f0fc=(lane>>3)<<5;
    float4 wr[32];
    #pragma unroll
    for (int t=0;t<32;++t) wr[t]=*(const float4*)(fcW+(L<<16)+(f0fc+t)*256+(qfc<<2));
    const float4 bb=*(const float4*)(fcb+(L<<8)+(qfc<<2));
    float4 lw={0,0,0,0}, lb2={0,0,0,0};
    if (L<3){ lw=*(const float4*)(lnw+(L<<8)+(qfc<<2)); lb2=*(const float4*)(lnb+(L<<8)+(qfc<<2)); }
    if (lt==0){
      if (L==0){
        const u32* f1=(const u32*)(wsbuf+128);
        const u32* f2=(const u32*)(wsbuf+384);
        while (__hip_atomic_load(f1,__ATOMIC_ACQUIRE,__HIP_MEMORY_SCOPE_AGENT)!=MAGIC ||
               __hip_atomic_load(f2,__ATOMIC_ACQUIRE,__HIP_MEMORY_SCOPE_AGENT)!=MAGIC)
          __builtin_amdgcn_s_sleep(1);
      } else {
        const u32* f1=(const u32*)(wsbuf+512+(L-1)*512+256);
        while (__hip_atomic_load(f1,__ATOMIC_ACQUIRE,__HIP_MEMORY_SCOPE_AGENT)!=MAGIC)
          __builtin_amdgcn_s_sleep(1);
      }
    }
    bar_lds();
    if (lt<256){
      const float* src = (L==0) ? (wsbuf + (lt<128 ? lt : 128+lt))
                                : (wsbuf + 512 + (L-1)*512 + lt);
      fcin[lt]=__hip_atomic_load(src,__ATOMIC_RELAXED,__HIP_MEMORY_SCOPE_AGENT);
    }
    bar_lds();
    float4 a={0.f,0.f,0.f,0.f};
    #pragma unroll
    for (int t=0;t<32;++t){
      const float zv=fcin[f0fc+t];
      a.x+=zv*wr[t].x; a.y+=zv*wr[t].y; a.z+=zv*wr[t].z; a.w+=zv*wr[t].w;
    }
    #pragma unroll
    for (int m=8;m<64;m<<=1){
      a.x+=__shfl_xor(a.x,m,64); a.y+=__shfl_xor(a.y,m,64);
      a.z+=__shfl_xor(a.z,m,64); a.w+=__shfl_xor(a.w,m,64);
    }
    if (L==3){
      if (lane<8){
        float4 r; r.x=a.x+bb.x; r.y=a.y+bb.y; r.z=a.z+bb.z; r.w=a.w+bb.w;
        *(float4*)(out+(qfc<<2))=r;
      }
      return;
    }
    const bool act=(lane<8);
    float4 hv={0.f,0.f,0.f,0.f};
    if (act){
      hv.x=a.x+bb.x; hv.y=a.y+bb.y; hv.z=a.z+bb.z; hv.w=a.w+bb.w;
      float s=hv.x+hv.y+hv.z+hv.w;
      float s2=hv.x*hv.x+hv.y*hv.y+hv.z*hv.z+hv.w*hv.w;
      #pragma unroll
      for (int m=1;m<8;m<<=1){ s+=__shfl_xor(s,m,64); s2+=__shfl_xor(s2,m,64); }
      if (lane==0){ wpart[wid]=s; wpart[8+wid]=s2; }
    }
    bar_lds();
    if (act){
      float S=0.f,S2=0.f;
      #pragma unroll
      for (int w2=0;w2<8;++w2){ S+=wpart[w2]; S2+=wpart[8+w2]; }
      const float mu=S*(1.f/256.f);
      const float ri=rsqrtf(S2*(1.f/256.f)-mu*mu+1e-5f);
      float* dst=wsbuf+512+L*512+(qfc<<2);
      __hip_atomic_store(dst+0,fmaxf((hv.x-mu)*ri*lw.x+lb2.x,0.f),__ATOMIC_RELAXED,__HIP_MEMORY_SCOPE_AGENT);
      __hip_atomic_store(dst+1,fmaxf((hv.y-mu)*ri*lw.y+lb2.y,0.f),__ATOMIC_RELAXED,__HIP_MEMORY_SCOPE_AGENT);
      __hip_atomic_store(dst+2,fmaxf((hv.z-mu)*ri*lw.z+lb2.z,0.f),__ATOMIC_RELAXED,__HIP_MEMORY_SCOPE_AGENT);
      __hip_atomic_store(dst+3,fmaxf((hv.w-mu)*ri*lw.w+lb2.w,0.f),__ATOMIC_RELAXED,__HIP_MEMORY_SCOPE_AGENT);
    }
    __threadfence();
    bar_lds();
    if (lt==0) __hip_atomic_store((u32*)(wsbuf+512+L*512+256),MAGIC,__ATOMIC_RELEASE,__HIP_MEMORY_SCOPE_AGENT);
    return;
  }

  // ============ GNN worker blocks (bids 0,1) ============
  const int br = bid;
  const float* x0    = br ? sp_x    : gp_x;
  const int*   srcg  = br ? sp_src  : gp_src;
  const int*   dstg  = br ? sp_dst  : gp_dst;
  const float* W0    = br ? s_W0    : g_W0;
  const float* Wl    = br ? s_W     : g_W;
  const float* bl    = br ? s_b     : g_b;
  const float* wrel  = br ? s_pWrel : g_pWrel;
  const float* brel  = br ? s_pbrel : g_pbrel;
  const float* wroot = br ? s_pWroot: g_pWroot;
  const float* linWg = br ? s_linW  : g_linW;
  const float* linb  = br ? s_linb  : g_linb;
  float* wsOut = wsbuf + br*256;
  u32*   wsFlag = (u32*)(wsbuf + 128 + br*256);

  // ---- t0 global preloads (OLDEST in vmcnt order) ----
  float xv[4];
  #pragma unroll
  for (int r=0;r<4;++r){
    const int i=lt+(r<<9), v=i>>7, f=i&127;
    xv[r] = (f<45)? x0[v*45+f] : 0.f;
  }
  int es=0, ed=0; float emk=0.f;
  if (lt<64){ es=srcg[lt]; ed=dstg[lt]; emk=1.f; }
  const float4 brelv = *(const float4*)brel;
  const float4 blv0=*(const float4*)(bl       + ((lt&31)<<2));
  const float4 blv1=*(const float4*)(bl + 128 + (((lt>>1)&31)<<2));
  const float4 blv2=*(const float4*)(bl + 256 + (((lt>>2)&31)<<2));
  const float4 blv3=*(const float4*)(bl + 384 + (((lt>>3)&31)<<2));
  const float linb_s = linb[lt>>2];
  asm volatile("" ::: "memory");
  // DMA: score weights (tiny) then W1 (8 instr/wave)
  stageW(wrel,  wrelL,  512, wid, lane);
  stageW(wroot, wrootL, 512, wid, lane);
  stageW(Wl,    slotA, 16384, wid, lane);            // W1

  // wave-0 dense A/M builder; summands per cell identical -> order-independent
  auto build_dense=[&](int kk, float wlane, bool with_ts){
    const float4 z4={0.f,0.f,0.f,0.f};
    *(float4*)&Adn[lt<<2]=z4;
    *(float4*)&Mdn[lt<<2]=z4;
    const bool act=(emk!=0.f);
    int mycnt=0;
    for (int v=0;v<kk;++v){
      const unsigned long long m=__ballot(act&&(ed==v));
      if (lt==v) mycnt=__popcll(m);
    }
    const float dinvl=rsqrtf(1.f+(float)mycnt);
    const float dvs=__shfl(dinvl,es,64);
    const float dvd=__shfl(dinvl,ed,64);
    if (act){
      atomicAdd(&Adn[ed*16+es], dvs*dvd*wlane);
      atomicAdd(&Mdn[ed*16+es], 1.f);
    }
    if (lt<kk){
      const float tv = with_ts ? tsA[lt] : 1.f;
      atomicAdd(&Adn[lt*17], dinvl*dinvl*tv);
    }
  };
  auto doE=[&](int n,int k,float bv,int nparts,bool rebuild){
    if (lt<64){
      float d1s=0.f, d2s=0.f;
      if (lt<n){
        for (int p=0;p<nparts;++p){ d1s+=d1P[(lt<<2)+p]; d2s+=d2P[(lt<<2)+p]; }
      }
      float sc=-INFINITY;
      if (lt<n){
        float acc=d2s+bv;
        for (int u=0;u<n;++u) acc += Mdn[lt*16+u]*__shfl(d1s,u,64);
        sc=acc;
      }
      int rank=0;
      for (int u=0;u<n;++u){
        const float su=__shfl(sc,u,64);
        rank += (su>sc || (su==sc && u<lt)) ? 1:0;
      }
      const int kept=(lt<n && rank<k)?1:0;
      const int pos=kept?rank:0;
      const float tval=kept?tanhf(sc):0.f;
      if (kept){ permA[rank]=lt; tsA[rank]=tval; }
      const float ts_src=__shfl(tval,es,64);       // es still OLD index
      const int ks=__shfl(kept,es,64), kd=__shfl(kept,ed,64);
      const int ps=__shfl(pos,es,64),  pd=__shfl(pos,ed,64);
      emk *= (float)(ks&kd);
      es=ps; ed=pd;
      if (rebuild) build_dense(k, ts_src, true);
    }
  };
  auto doB=[&](int n){
    if (lt<(n<<5)){
      const int v=lt>>5, j4=(lt&31)<<2;
      float4 a={0.f,0.f,0.f,0.f};
      for (int u=0;u<n;++u){
        const float w=Adn[v*16+u];
        const float4 xs=*(const float4*)&XBx[permA[u]][j4];
        a.x+=w*xs.x; a.y+=w*xs.y; a.z+=w*xs.z; a.w+=w*xs.w;
      }
      *(float4*)&ZBraw[(v<<7)+j4]=a;
    }
  };

  // P1: stage x + build layer-0 A/M
  #pragma unroll
  for (int r=0;r<4;++r){
    const int i=lt+(r<<9), v=i>>7, f=i&127;
    XBx[v][f]=xv[r];
  }
  if (lt<64) build_dense(16, 1.f, false);
  bar_lds();

  // P2: B0 — z0 = A @ x (16 rows x 48 cols) into ZBraw stride 48
  if (lt<256){
    const int v=lt>>4, j4=(lt&15)<<2;
    if (j4<48){
      float4 a={0.f,0.f,0.f,0.f};
      for (int u=0;u<16;++u){
        const float w=Adn[v*16+u];
        const float4 xs=*(const float4*)&XBx[u][j4];
        a.x+=w*xs.x; a.y+=w*xs.y; a.z+=w*xs.z; a.w+=w*xs.w;
      }
      *(float4*)&ZBraw[v*48+j4]=a;
    }
  }
  bar_vm8();                                // retires wrel/wroot; W1 flies

  // P3: C0 — x = relu(z0 @ W0 + b0) + score-dot epilogue (W0 global batches)
  {
    const int v=lt>>5, c4=lt&31, j4=c4<<2;
    const float* zrow=&ZBraw[v*48];
    float4 a={0.f,0.f,0.f,0.f};
    #pragma unroll
    for (int bb=0;bb<2;++bb){
      float4 wr[16]; float zr[16];
      #pragma unroll
      for (int t=0;t<16;++t){ wr[t]=*(const float4*)(W0+(bb*16+t)*128+j4); zr[t]=zrow[bb*16+t]; }
      #pragma unroll
      for (int t=0;t<16;++t){ a.x+=zr[t]*wr[t].x; a.y+=zr[t]*wr[t].y; a.z+=zr[t]*wr[t].z; a.w+=zr[t]*wr[t].w; }
    }
    { float4 wr[13]; float zr[13];
      #pragma unroll
      for (int t=0;t<13;++t){ wr[t]=*(const float4*)(W0+(32+t)*128+j4); zr[t]=zrow[32+t]; }
      #pragma unroll
      for (int t=0;t<13;++t){ a.x+=zr[t]*wr[t].x; a.y+=zr[t]*wr[t].y; a.z+=zr[t]*wr[t].z; a.w+=zr[t]*wr[t].w; }
    }
    float4 ox;
    ox.x=fmaxf(a.x+blv0.x,0.f); ox.y=fmaxf(a.y+blv0.y,0.f);
    ox.z=fmaxf(a.z+blv0.z,0.f); ox.w=fmaxf(a.w+blv0.w,0.f);
    *(float4*)&XBx[v][j4]=ox;
    const float4 wr4=*(const float4*)&wrelL[j4];
    const float4 wo4=*(const float4*)&wrootL[j4];
    float p1=ox.x*wr4.x+ox.y*wr4.y+ox.z*wr4.z+ox.w*wr4.w;
    float p2=ox.x*wo4.x+ox.y*wo4.y+ox.z*wo4.z+ox.w*wo4.w;
    p1=hsum32(p1); p2=hsum32(p2);
    if ((lane&31)==0){
      const int vv=(wid<<1)|(lane>>5);
      d1P[vv<<2]=p1; d2P[vv<<2]=p2;
    }
  }
  stageW(Wl+16384, slotB, 16384, wid, lane);         // W2 (younger than all W0 loads)
  bar_lds();

  doE(16, 8, brelv.x, 1, true);  bar_lds();          // E0
  doB(8);                        bar_vm8();          // B1; W1 retired, W2 flies
  cfused<1>(lt, slotA, ZBraw, XBx, wrelL, wrootL, blv1, d1P, d2P);
  bar_lds();                                          // C1
  stageW(Wl+32768, slotA, 16384, wid, lane);          // W3 (slotA free)
  doE(8, 4, brelv.y, 1, true);   bar_lds();          // E1
  doB(4);                        bar_vm8();          // B2; W2 retired, W3 flies
  cfused<2>(lt, slotB, ZBraw, XBx, wrelL, wrootL, blv2, d1P, d2P);
  bar_lds();                                          // C2
  stageW(linWg, slotB, 16384, wid, lane);             // linW (slotB free)
  doE(4, 2, brelv.z, 2, true);   bar_lds();          // E2
  doB(2);                        bar_vm8();          // B3; W3 retired, linW flies
  cfused<3>(lt, slotA, ZBraw, XBx, wrelL, wrootL, blv3, d1P, d2P);
  bar_lds();                                          // C3
  doE(2, 1, brelv.w, 4, false);  bar_vm0();          // E3; drain linW

  // readout fused: y[oj] = ts0 * (x[perm0] . linW[:,oj]) + linb[oj]
  {
    const int oj=lt>>2, fh=lt&3;
    const int prow=permA[0];
    float p=0.f;
    #pragma unroll
    for (int i=0;i<32;++i){
      const int f=(fh<<5)+i;
      p += XBx[prow][f]*slotB[f*128+oj];
    }
    p+=__shfl_xor(p,1,64); p+=__shfl_xor(p,2,64);
    if (fh==0) yA[oj]=p*tsA[0]+linb_s;
  }
  bar_lds();
  // log-softmax + deliver
  if (lt<128){
    const int ln=lt&63;
    const float a0=yA[ln], b0=yA[64+ln];
    const float m=wmax(fmaxf(a0,b0));
    const float sum=wsum(expf(a0-m)+expf(b0-m));
    const float lse=m+logf(sum);
    __hip_atomic_store(&wsOut[lt], yA[lt]-lse, __ATOMIC_RELAXED, __HIP_MEMORY_SCOPE_AGENT);
  }
  __threadfence();
  bar_lds();
  if (lt==0) __hip_atomic_store(wsFlag, MAGIC, __ATOMIC_RELEASE, __HIP_MEMORY_SCOPE_AGENT);
}

extern "C" void kernel_launch(void* const* d_in, const int* in_sizes, int n_in,
                              void* d_out, int out_size, void* d_ws, size_t ws_size,
                              hipStream_t stream){
  // setup_inputs() DICT order (fc/ln block precedes gnn params):
  //  0 gp_x  1 sp_x  2 gp_src  3 gp_dst  4 sp_src  5 sp_dst
  //  6 fcW   7 fcb   8 lnw     9 lnb
  // 10 g_W0 11 g_W  12 g_b   13 g_pWrel 14 g_pbrel 15 g_pWroot 16 g_linW 17 g_linb
  // 18 s_W0 19 s_W  20 s_b   21 s_pWrel 22 s_pbrel 23 s_pWroot 24 s_linW 25 s_linb
  net_kernel<<<16,512,0,stream>>>(
    (const float*)d_in[0],(const float*)d_in[1],
    (const int*)d_in[2],(const int*)d_in[3],(const int*)d_in[4],(const int*)d_in[5],
    (const float*)d_in[10],(const float*)d_in[11],(const float*)d_in[12],(const float*)d_in[13],
    (const float*)d_in[14],(const float*)d_in[15],(const float*)d_in[16],(const float*)d_in[17],
    (const float*)d_in[18],(const float*)d_in[19],(const float*)d_in[20],(const float*)d_in[21],
    (const float*)d_in[22],(const float*)d_in[23],(const float*)d_in[24],(const float*)d_in[25],
    (const float*)d_in[6],(const float*)d_in[7],(const float*)d_in[8],(const float*)d_in[9],
    (float*)d_ws,(float*)d_out);
}

// Round 11
// 24.183 us; speedup vs baseline: 1.3562x; 1.1333x over previous
//
#include <hip/hip_runtime.h>
#include <math.h>

#define MAGIC 0x5F3759DFu
typedef unsigned int u32;

__device__ __forceinline__ void bar_lds(){
  asm volatile("s_waitcnt lgkmcnt(0)\n\ts_barrier" ::: "memory");
}
__device__ __forceinline__ void bar_vm0(){
  asm volatile("s_waitcnt vmcnt(0) lgkmcnt(0)\n\ts_barrier" ::: "memory");
}
// counted: let the youngest in-flight stageW (8 instr/wave) keep flying
__device__ __forceinline__ void bar_vm8(){
  asm volatile("s_waitcnt vmcnt(8) lgkmcnt(0)\n\ts_barrier" ::: "memory");
}

__device__ inline float wsum(float v){
  #pragma unroll
  for (int o=32;o;o>>=1) v += __shfl_xor(v,o,64);
  return v;
}
__device__ inline float wmax(float v){
  #pragma unroll
  for (int o=32;o;o>>=1) v = fmaxf(v,__shfl_xor(v,o,64));
  return v;
}
__device__ inline float hsum32(float v){
  #pragma unroll
  for (int o=16;o;o>>=1) v += __shfl_xor(v,o,64);
  return v;
}
__device__ __forceinline__ void stageW(const float* g, float* l, int nfloats,
                                       int wid, int lane){
  const int nch = nfloats>>8;
  for (int c=wid; c<nch; c+=8)
    __builtin_amdgcn_global_load_lds(
      (__attribute__((address_space(1))) u32*)(void*)(g+(c<<8)+(lane<<2)),
      (__attribute__((address_space(3))) u32*)(void*)(l+(c<<8)), 16, 0, 0);
}
__device__ __forceinline__ void pf(const float* p, int nfloats, int tid){
  float4 acc={0.f,0.f,0.f,0.f};
  const int nq=nfloats>>2;
  for (int i=tid;i<nq;i+=512){
    const float4 v=((const float4*)p)[i];
    acc.x+=v.x; acc.y+=v.y; acc.z+=v.z; acc.w+=v.w;
  }
  asm volatile("" :: "v"(acc.x),"v"(acc.y),"v"(acc.z),"v"(acc.w));
}

// ws float layout: p_g[0..127] flag@128 | p_s[256..383] flag@384
// H0[512..767] flag@768 | H1[1024..1279] flag@1280 | H2[1536..1791] flag@1792
__global__ __launch_bounds__(512,1) void net_kernel(
    const float* __restrict__ gp_x, const float* __restrict__ sp_x,
    const int* __restrict__ gp_src, const int* __restrict__ gp_dst,
    const int* __restrict__ sp_src, const int* __restrict__ sp_dst,
    const float* __restrict__ g_W0, const float* __restrict__ g_W,
    const float* __restrict__ g_b,  const float* __restrict__ g_pWrel,
    const float* __restrict__ g_pbrel, const float* __restrict__ g_pWroot,
    const float* __restrict__ g_linW, const float* __restrict__ g_linb,
    const float* __restrict__ s_W0, const float* __restrict__ s_W,
    const float* __restrict__ s_b,  const float* __restrict__ s_pWrel,
    const float* __restrict__ s_pbrel, const float* __restrict__ s_pWroot,
    const float* __restrict__ s_linW, const float* __restrict__ s_linb,
    const float* __restrict__ fcW, const float* __restrict__ fcb,
    const float* __restrict__ lnw, const float* __restrict__ lnb,
    float* __restrict__ wsbuf, float* __restrict__ out)
{
  __shared__ __align__(16) float slotA[16384];   // W1 -> W3 (DMA)
  __shared__ __align__(16) float slotB[16384];   // W2 -> linW (DMA)
  __shared__ __align__(16) float XBx[16][128];
  __shared__ __align__(16) float ZBraw[1024];    // z0[16][48] then z[8][128]
  __shared__ __align__(16) float PBf[2048];      // C-phase partials (512 float4)
  __shared__ __align__(16) float wrelL[512], wrootL[512];
  __shared__ __align__(16) float Adn[256], Mdn[256];
  __shared__ float d1P[64], d2P[64];
  __shared__ float yA[128];
  __shared__ float tsA[8]; __shared__ int permA[8];
  __shared__ float fcin[256]; __shared__ float wpart[16];

  const int lt  = threadIdx.x;
  const int bid = blockIdx.x;
  const int wid = lt>>6, lane = lt&63;

  // ============ prefetch army (bids 6..19): fine slices, ~2-3us each ============
  if (bid >= 6){
    if (bid==6){ pf(g_W0,5760,lt); pf(g_pWrel,512,lt); pf(g_pWroot,512,lt);
                 pf(g_b,512,lt);   pf(g_linb,128,lt); }
    else if (bid==7){ pf(s_W0,5760,lt); pf(s_pWrel,512,lt); pf(s_pWroot,512,lt);
                 pf(s_b,512,lt);   pf(s_linb,128,lt); }
    else if (bid<=11) pf(g_W + (bid-8)*12288, 12288, lt);
    else if (bid<=15) pf(s_W + (bid-12)*12288, 12288, lt);
    else if (bid<=17) pf(g_linW + (bid-16)*8192, 8192, lt);
    else              pf(s_linW + (bid-18)*8192, 8192, lt);
    return;
  }

  // ============ FC pipeline blocks (bids 2..5, L=bid-2) — proven R8 ============
  if (bid >= 2){
    const int L = bid-2;
    const int qfc=(wid<<3)+(lane&7), f0fc=(lane>>3)<<5;
    float4 wr[32];
    #pragma unroll
    for (int t=0;t<32;++t) wr[t]=*(const float4*)(fcW+(L<<16)+(f0fc+t)*256+(qfc<<2));
    const float4 bb=*(const float4*)(fcb+(L<<8)+(qfc<<2));
    float4 lw={0,0,0,0}, lb2={0,0,0,0};
    if (L<3){ lw=*(const float4*)(lnw+(L<<8)+(qfc<<2)); lb2=*(const float4*)(lnb+(L<<8)+(qfc<<2)); }
    if (lt==0){
      if (L==0){
        const u32* f1=(const u32*)(wsbuf+128);
        const u32* f2=(const u32*)(wsbuf+384);
        while (__hip_atomic_load(f1,__ATOMIC_ACQUIRE,__HIP_MEMORY_SCOPE_AGENT)!=MAGIC ||
               __hip_atomic_load(f2,__ATOMIC_ACQUIRE,__HIP_MEMORY_SCOPE_AGENT)!=MAGIC)
          __builtin_amdgcn_s_sleep(1);
      } else {
        const u32* f1=(const u32*)(wsbuf+512+(L-1)*512+256);
        while (__hip_atomic_load(f1,__ATOMIC_ACQUIRE,__HIP_MEMORY_SCOPE_AGENT)!=MAGIC)
          __builtin_amdgcn_s_sleep(1);
      }
    }
    bar_lds();
    if (lt<256){
      const float* src = (L==0) ? (wsbuf + (lt<128 ? lt : 128+lt))
                                : (wsbuf + 512 + (L-1)*512 + lt);
      fcin[lt]=__hip_atomic_load(src,__ATOMIC_RELAXED,__HIP_MEMORY_SCOPE_AGENT);
    }
    bar_lds();
    float4 a={0.f,0.f,0.f,0.f};
    #pragma unroll
    for (int t=0;t<32;++t){
      const float zv=fcin[f0fc+t];
      a.x+=zv*wr[t].x; a.y+=zv*wr[t].y; a.z+=zv*wr[t].z; a.w+=zv*wr[t].w;
    }
    #pragma unroll
    for (int m=8;m<64;m<<=1){
      a.x+=__shfl_xor(a.x,m,64); a.y+=__shfl_xor(a.y,m,64);
      a.z+=__shfl_xor(a.z,m,64); a.w+=__shfl_xor(a.w,m,64);
    }
    if (L==3){
      if (lane<8){
        float4 r; r.x=a.x+bb.x; r.y=a.y+bb.y; r.z=a.z+bb.z; r.w=a.w+bb.w;
        *(float4*)(out+(qfc<<2))=r;
      }
      return;
    }
    const bool act=(lane<8);
    float4 hv={0.f,0.f,0.f,0.f};
    if (act){
      hv.x=a.x+bb.x; hv.y=a.y+bb.y; hv.z=a.z+bb.z; hv.w=a.w+bb.w;
      float s=hv.x+hv.y+hv.z+hv.w;
      float s2=hv.x*hv.x+hv.y*hv.y+hv.z*hv.z+hv.w*hv.w;
      #pragma unroll
      for (int m=1;m<8;m<<=1){ s+=__shfl_xor(s,m,64); s2+=__shfl_xor(s2,m,64); }
      if (lane==0){ wpart[wid]=s; wpart[8+wid]=s2; }
    }
    bar_lds();
    if (act){
      float S=0.f,S2=0.f;
      #pragma unroll
      for (int w2=0;w2<8;++w2){ S+=wpart[w2]; S2+=wpart[8+w2]; }
      const float mu=S*(1.f/256.f);
      const float ri=rsqrtf(S2*(1.f/256.f)-mu*mu+1e-5f);
      float* dst=wsbuf+512+L*512+(qfc<<2);
      __hip_atomic_store(dst+0,fmaxf((hv.x-mu)*ri*lw.x+lb2.x,0.f),__ATOMIC_RELAXED,__HIP_MEMORY_SCOPE_AGENT);
      __hip_atomic_store(dst+1,fmaxf((hv.y-mu)*ri*lw.y+lb2.y,0.f),__ATOMIC_RELAXED,__HIP_MEMORY_SCOPE_AGENT);
      __hip_atomic_store(dst+2,fmaxf((hv.z-mu)*ri*lw.z+lb2.z,0.f),__ATOMIC_RELAXED,__HIP_MEMORY_SCOPE_AGENT);
      __hip_atomic_store(dst+3,fmaxf((hv.w-mu)*ri*lw.w+lb2.w,0.f),__ATOMIC_RELAXED,__HIP_MEMORY_SCOPE_AGENT);
    }
    __threadfence();
    bar_lds();
    if (lt==0) __hip_atomic_store((u32*)(wsbuf+512+L*512+256),MAGIC,__ATOMIC_RELEASE,__HIP_MEMORY_SCOPE_AGENT);
    return;
  }

  // ============ GNN worker blocks (bids 0,1) ============
  const int br = bid;
  const float* x0    = br ? sp_x    : gp_x;
  const int*   srcg  = br ? sp_src  : gp_src;
  const int*   dstg  = br ? sp_dst  : gp_dst;
  const float* W0    = br ? s_W0    : g_W0;
  const float* Wl    = br ? s_W     : g_W;
  const float* bl    = br ? s_b     : g_b;
  const float* wrel  = br ? s_pWrel : g_pWrel;
  const float* brel  = br ? s_pbrel : g_pbrel;
  const float* wroot = br ? s_pWroot: g_pWroot;
  const float* linWg = br ? s_linW  : g_linW;
  const float* linb  = br ? s_linb  : g_linb;
  float* wsOut = wsbuf + br*256;
  u32*   wsFlag = (u32*)(wsbuf + 128 + br*256);

  // ---- t0 global preloads (OLDEST in vmcnt order) ----
  float xv[4];
  #pragma unroll
  for (int r=0;r<4;++r){
    const int i=lt+(r<<9), v=i>>7, f=i&127;
    xv[r] = (f<45)? x0[v*45+f] : 0.f;
  }
  int es=0, ed=0; float emk=0.f;
  if (lt<64){ es=srcg[lt]; ed=dstg[lt]; emk=1.f; }
  const float4 brelv = *(const float4*)brel;
  const int bi4=(lt&31)<<2;
  const float4 blv0=*(const float4*)(bl       + bi4);
  const float4 blv1=*(const float4*)(bl + 128 + bi4);
  const float4 blv2=*(const float4*)(bl + 256 + bi4);
  const float4 blv3=*(const float4*)(bl + 384 + bi4);
  const float linb_s = linb[lt>>2];
  asm volatile("" ::: "memory");
  stageW(wrel,  wrelL,  512, wid, lane);
  stageW(wroot, wrootL, 512, wid, lane);
  stageW(Wl,    slotA, 16384, wid, lane);            // W1

  // wave-0 dense A/M builder (per-cell summands identical -> deterministic)
  auto build_dense=[&](int kk, float wlane, bool with_ts){
    const float4 z4={0.f,0.f,0.f,0.f};
    *(float4*)&Adn[lt<<2]=z4;
    *(float4*)&Mdn[lt<<2]=z4;
    const bool act=(emk!=0.f);
    int mycnt=0;
    for (int v=0;v<kk;++v){
      const unsigned long long m=__ballot(act&&(ed==v));
      if (lt==v) mycnt=__popcll(m);
    }
    const float dinvl=rsqrtf(1.f+(float)mycnt);
    const float dvs=__shfl(dinvl,es,64);
    const float dvd=__shfl(dinvl,ed,64);
    if (act){
      atomicAdd(&Adn[ed*16+es], dvs*dvd*wlane);
      atomicAdd(&Mdn[ed*16+es], 1.f);
    }
    if (lt<kk){
      const float tv = with_ts ? tsA[lt] : 1.f;
      atomicAdd(&Adn[lt*17], dinvl*dinvl*tv);
    }
  };
  auto doE=[&](int n,int k,float bv,bool rebuild){
    if (lt<64){
      const float d1s=(lt<n)? d1P[lt<<2] : 0.f;
      float sc=-INFINITY;
      if (lt<n){
        float acc=d2P[lt<<2]+bv;
        for (int u=0;u<n;++u) acc += Mdn[lt*16+u]*__shfl(d1s,u,64);
        sc=acc;
      }
      int rank=0;
      for (int u=0;u<n;++u){
        const float su=__shfl(sc,u,64);
        rank += (su>sc || (su==sc && u<lt)) ? 1:0;
      }
      const int kept=(lt<n && rank<k)?1:0;
      const int pos=kept?rank:0;
      const float tval=kept?tanhf(sc):0.f;
      if (kept){ permA[rank]=lt; tsA[rank]=tval; }
      const float ts_src=__shfl(tval,es,64);       // es still OLD index
      const int ks=__shfl(kept,es,64), kd=__shfl(kept,ed,64);
      const int ps=__shfl(pos,es,64),  pd=__shfl(pos,ed,64);
      emk *= (float)(ks&kd);
      es=ps; ed=pd;
      if (rebuild) build_dense(k, ts_src, true);
    }
  };
  auto doB=[&](int n){
    if (lt<(n<<5)){
      const int v=lt>>5, j4=(lt&31)<<2;
      float4 a={0.f,0.f,0.f,0.f};
      for (int u=0;u<n;++u){
        const float w=Adn[v*16+u];
        const float4 xs=*(const float4*)&XBx[permA[u]][j4];
        a.x+=w*xs.x; a.y+=w*xs.y; a.z+=w*xs.z; a.w+=w*xs.w;
      }
      *(float4*)&ZBraw[(v<<7)+j4]=a;
    }
  };
  // C-main (R8 conflict-free layout): fh from HIGH bits -> row uniform per wave
  auto cmain=[&](const float* slot, int L){
    const int sh=9-L, nq=512>>L, CH=128>>L;
    const int q=lt&(nq-1), fh=lt>>sh;
    const int v=q>>5, c4=q&31, f0=fh*CH;
    const float* zrow=&ZBraw[v<<7];
    float4 a={0.f,0.f,0.f,0.f};
    for (int f=0; f<CH; ++f){
      const float zv=zrow[f0+f];
      const float4 w4=*(const float4*)&slot[(f0+f)*128+(c4<<2)];
      a.x+=zv*w4.x; a.y+=zv*w4.y; a.z+=zv*w4.z; a.w+=zv*w4.w;
    }
    ((float4*)PBf)[lt]=a;
  };
  // C-reduce + relu + score-dot epilogue
  auto creduce=[&](int L, float4 bl4){
    const int nq=512>>L, SPL=1<<L;
    if (lt<nq){
      const int v=lt>>5, c4=lt&31;
      float4 acc=bl4;
      for (int s=0;s<SPL;++s){
        const float4 p=((const float4*)PBf)[s*nq+lt];
        acc.x+=p.x; acc.y+=p.y; acc.z+=p.z; acc.w+=p.w;
      }
      float4 o;
      o.x=fmaxf(acc.x,0.f); o.y=fmaxf(acc.y,0.f);
      o.z=fmaxf(acc.z,0.f); o.w=fmaxf(acc.w,0.f);
      *(float4*)&XBx[v][c4<<2]=o;
      const float4 wr4=*(const float4*)&wrelL[(L<<7)+(c4<<2)];
      const float4 wo4=*(const float4*)&wrootL[(L<<7)+(c4<<2)];
      float p1=o.x*wr4.x+o.y*wr4.y+o.z*wr4.z+o.w*wr4.w;
      float p2=o.x*wo4.x+o.y*wo4.y+o.z*wo4.z+o.w*wo4.w;
      p1=hsum32(p1); p2=hsum32(p2);
      if ((lane&31)==0){ d1P[v<<2]=p1; d2P[v<<2]=p2; }
    }
  };

  // P1: stage x + layer-0 A/M
  #pragma unroll
  for (int r=0;r<4;++r){
    const int i=lt+(r<<9), v=i>>7, f=i&127;
    XBx[v][f]=xv[r];
  }
  if (lt<64) build_dense(16, 1.f, false);
  bar_lds();

  // P2: B0 — z0 = A @ x (16 x 48) stride 48
  if (lt<256){
    const int v=lt>>4, j4=(lt&15)<<2;
    if (j4<48){
      float4 a={0.f,0.f,0.f,0.f};
      for (int u=0;u<16;++u){
        const float w=Adn[v*16+u];
        const float4 xs=*(const float4*)&XBx[u][j4];
        a.x+=w*xs.x; a.y+=w*xs.y; a.z+=w*xs.z; a.w+=w*xs.w;
      }
      *(float4*)&ZBraw[v*48+j4]=a;
    }
  }
  bar_vm8();                                  // retire wrel/wroot; W1 flies

  // P3: C0 — x = relu(z0 @ W0 + b0) + score-dot epilogue (W0 global)
  {
    const int v=lt>>5, c4=lt&31, j4=c4<<2;
    const float* zrow=&ZBraw[v*48];
    float4 a={0.f,0.f,0.f,0.f};
    #pragma unroll
    for (int bb=0;bb<2;++bb){
      float4 wr[16]; float zr[16];
      #pragma unroll
      for (int t=0;t<16;++t){ wr[t]=*(const float4*)(W0+(bb*16+t)*128+j4); zr[t]=zrow[bb*16+t]; }
      #pragma unroll
      for (int t=0;t<16;++t){ a.x+=zr[t]*wr[t].x; a.y+=zr[t]*wr[t].y; a.z+=zr[t]*wr[t].z; a.w+=zr[t]*wr[t].w; }
    }
    { float4 wr[13]; float zr[13];
      #pragma unroll
      for (int t=0;t<13;++t){ wr[t]=*(const float4*)(W0+(32+t)*128+j4); zr[t]=zrow[32+t]; }
      #pragma unroll
      for (int t=0;t<13;++t){ a.x+=zr[t]*wr[t].x; a.y+=zr[t]*wr[t].y; a.z+=zr[t]*wr[t].z; a.w+=zr[t]*wr[t].w; }
    }
    float4 ox;
    ox.x=fmaxf(a.x+blv0.x,0.f); ox.y=fmaxf(a.y+blv0.y,0.f);
    ox.z=fmaxf(a.z+blv0.z,0.f); ox.w=fmaxf(a.w+blv0.w,0.f);
    *(float4*)&XBx[v][j4]=ox;
    const float4 wr4=*(const float4*)&wrelL[j4];
    const float4 wo4=*(const float4*)&wrootL[j4];
    float p1=ox.x*wr4.x+ox.y*wr4.y+ox.z*wr4.z+ox.w*wr4.w;
    float p2=ox.x*wo4.x+ox.y*wo4.y+ox.z*wo4.z+ox.w*wo4.w;
    p1=hsum32(p1); p2=hsum32(p2);
    if ((lane&31)==0){
      const int vv=(wid<<1)|(lane>>5);
      d1P[vv<<2]=p1; d2P[vv<<2]=p2;
    }
  }
  stageW(Wl+16384, slotB, 16384, wid, lane);   // W2 (younger than W0 loads)
  bar_lds();

  doE(16, 8, brelv.x, true);   bar_lds();      // E0
  doB(8);                      bar_vm8();      // B1 (W1 drained by C0 waits; W2 flies)
  cmain(slotA, 1);             bar_lds();      // C1m (W1, conflict-free)
  creduce(1, blv1);            bar_lds();      // C1r
  stageW(Wl+32768, slotA, 16384, wid, lane);   // W3 (slotA reads done)
  doE(8, 4, brelv.y, true);    bar_lds();      // E1
  doB(4);                      bar_vm8();      // B2 (W2 retired; W3 flies)
  cmain(slotB, 2);             bar_lds();      // C2m (W2)
  creduce(2, blv2);            bar_lds();      // C2r
  stageW(linWg, slotB, 16384, wid, lane);      // linW (slotB reads done)
  doE(4, 2, brelv.z, true);    bar_lds();      // E2
  doB(2);                      bar_vm8();      // B3 (W3 retired; linW flies)
  cmain(slotA, 3);             bar_lds();      // C3m (W3)
  creduce(3, blv3);            bar_lds();      // C3r
  doE(2, 1, brelv.w, false);   bar_vm0();      // E3; drain linW

  // readout fused: y[oj] = ts0 * (x[perm0] . linW[:,oj]) + linb[oj]
  {
    const int oj=lt>>2, fh=lt&3;
    const int prow=permA[0];
    float p=0.f;
    #pragma unroll
    for (int i=0;i<32;++i){
      const int f=(fh<<5)+i;
      p += XBx[prow][f]*slotB[f*128+oj];
    }
    p+=__shfl_xor(p,1,64); p+=__shfl_xor(p,2,64);
    if (fh==0) yA[oj]=p*tsA[0]+linb_s;
  }
  bar_lds();
  // log-softmax + deliver
  if (lt<128){
    const int ln=lt&63;
    const float a0=yA[ln], b0=yA[64+ln];
    const float m=wmax(fmaxf(a0,b0));
    const float sum=wsum(expf(a0-m)+expf(b0-m));
    const float lse=m+logf(sum);
    __hip_atomic_store(&wsOut[lt], yA[lt]-lse, __ATOMIC_RELAXED, __HIP_MEMORY_SCOPE_AGENT);
  }
  __threadfence();
  bar_lds();
  if (lt==0) __hip_atomic_store(wsFlag, MAGIC, __ATOMIC_RELEASE, __HIP_MEMORY_SCOPE_AGENT);
}

extern "C" void kernel_launch(void* const* d_in, const int* in_sizes, int n_in,
                              void* d_out, int out_size, void* d_ws, size_t ws_size,
                              hipStream_t stream){
  // setup_inputs() DICT order (fc/ln block precedes gnn params):
  //  0 gp_x  1 sp_x  2 gp_src  3 gp_dst  4 sp_src  5 sp_dst
  //  6 fcW   7 fcb   8 lnw     9 lnb
  // 10 g_W0 11 g_W  12 g_b   13 g_pWrel 14 g_pbrel 15 g_pWroot 16 g_linW 17 g_linb
  // 18 s_W0 19 s_W  20 s_b   21 s_pWrel 22 s_pbrel 23 s_pWroot 24 s_linW 25 s_linb
  net_kernel<<<20,512,0,stream>>>(
    (const float*)d_in[0],(const float*)d_in[1],
    (const int*)d_in[2],(const int*)d_in[3],(const int*)d_in[4],(const int*)d_in[5],
    (const float*)d_in[10],(const float*)d_in[11],(const float*)d_in[12],(const float*)d_in[13],
    (const float*)d_in[14],(const float*)d_in[15],(const float*)d_in[16],(const float*)d_in[17],
    (const float*)d_in[18],(const float*)d_in[19],(const float*)d_in[20],(const float*)d_in[21],
    (const float*)d_in[22],(const float*)d_in[23],(const float*)d_in[24],(const float*)d_in[25],
    (const float*)d_in[6],(const float*)d_in[7],(const float*)d_in[8],(const float*)d_in[9],
    (float*)d_ws,(float*)d_out);
}